// Round 3
// baseline (100.611 us; speedup 1.0000x reference)
//
#include <hip/hip_runtime.h>

#define N_CAND 8192
#define TILE   128
#define NTILES (N_CAND / TILE)   // 64
#define NBLK   (NTILES * NTILES) // 4096 partial slots

// ---------------------------------------------------------------------------
// Pass 1: each block owns a TILE x TILE tile of pair space (i-tile bi, j-tile
// bj). Lower-triangle tiles (bi > bj) write a zero partial and exit. Logits
// are pre-scaled by log2(e) at staging so the whole inner loop runs in the
// log2 domain; the final ln2 factor is applied once in pass 2.
//   softplus(d) = ln2 * ( max(dl,0) + log2(1 + 2^(-|dl|)) ),  dl = d*log2(e)
// ---------------------------------------------------------------------------
__global__ __launch_bounds__(TILE) void ranknet_pairs_kernel(
    const float* __restrict__ logits,
    const int*   __restrict__ rankings,
    float*       __restrict__ partials)
{
    const int bi = blockIdx.x;
    const int bj = blockIdx.y;
    const int b  = bj * NTILES + bi;
    const int tid = threadIdx.x;

    if (bi > bj) {               // dead tile: contribute an explicit zero
        if (tid == 0) partials[b] = 0.0f;
        return;
    }

    __shared__ float2 s_j[TILE];        // (logit*log2e, rank) for the j-chunk
    __shared__ float  s_part[TILE / 64];

    const float LOG2E = 1.4426950408889634f;

    const int i = bi * TILE + tid;
    const float lis = logits[i] * LOG2E;
    const float ri  = (float)rankings[i];        // ranks < 2^24: exact in f32

    const int j = bj * TILE + tid;
    s_j[tid] = make_float2(logits[j] * LOG2E, (float)rankings[j]);
    __syncthreads();

    float acc = 0.0f;
    if (bi != bj) {
        // off-diagonal: i < j holds for every pair in the tile
        #pragma unroll 8
        for (int jj = 0; jj < TILE; ++jj) {
            const float2 v = s_j[jj];            // broadcast ds_read_b64
            const float dl = v.x - lis;
            const float e  = __builtin_exp2f(-fabsf(dl));   // -|.| folds to src mod
            const float sp = fmaxf(dl, 0.0f) + __builtin_log2f(1.0f + e);
            const float w  = (v.y > ri) ? __builtin_amdgcn_rcpf(ri + v.y) : 0.0f;
            acc = fmaf(w, sp, acc);
        }
    } else {
        // diagonal tile: also require j > i
        #pragma unroll 8
        for (int jj = 0; jj < TILE; ++jj) {
            const float2 v = s_j[jj];
            const float dl = v.x - lis;
            const float e  = __builtin_exp2f(-fabsf(dl));
            const float sp = fmaxf(dl, 0.0f) + __builtin_log2f(1.0f + e);
            const bool act = (jj > tid) && (v.y > ri);
            const float w  = act ? __builtin_amdgcn_rcpf(ri + v.y) : 0.0f;
            acc = fmaf(w, sp, acc);
        }
    }

    // wave (64-lane) reduction, then cross-wave via LDS
    #pragma unroll
    for (int off = 32; off > 0; off >>= 1)
        acc += __shfl_down(acc, off, 64);
    if ((tid & 63) == 0) s_part[tid >> 6] = acc;
    __syncthreads();
    if (tid == 0) {
        float s = 0.0f;
        #pragma unroll
        for (int w = 0; w < TILE / 64; ++w) s += s_part[w];
        partials[b] = s;
    }
}

// ---------------------------------------------------------------------------
// Pass 2: single block reduces the 4096 partials; applies ln2 / N once.
// Plain store to d_out -> no memset node needed.
// ---------------------------------------------------------------------------
__global__ __launch_bounds__(256) void ranknet_reduce_kernel(
    const float* __restrict__ partials,
    float*       __restrict__ out)
{
    __shared__ float s_part[4];
    const int tid = threadIdx.x;

    float acc = 0.0f;
    #pragma unroll
    for (int k = tid; k < NBLK; k += 256)
        acc += partials[k];

    #pragma unroll
    for (int off = 32; off > 0; off >>= 1)
        acc += __shfl_down(acc, off, 64);
    if ((tid & 63) == 0) s_part[tid >> 6] = acc;
    __syncthreads();
    if (tid == 0) {
        float s = s_part[0] + s_part[1] + s_part[2] + s_part[3];
        const float LN2 = 0.6931471805599453f;
        out[0] = s * (LN2 / (float)N_CAND);
    }
}

extern "C" void kernel_launch(void* const* d_in, const int* in_sizes, int n_in,
                              void* d_out, int out_size, void* d_ws, size_t ws_size,
                              hipStream_t stream)
{
    const float* logits   = (const float*)d_in[0];
    const int*   rankings = (const int*)  d_in[1];
    float*       out      = (float*)d_out;
    float*       partials = (float*)d_ws;   // NBLK floats = 16 KB, well within ws

    dim3 grid(NTILES, NTILES);
    ranknet_pairs_kernel<<<grid, dim3(TILE), 0, stream>>>(logits, rankings, partials);
    ranknet_reduce_kernel<<<1, 256, 0, stream>>>(partials, out);
}

// Round 4
// 84.215 us; speedup vs baseline: 1.1947x; 1.1947x over previous
//
#include <hip/hip_runtime.h>

#define N_CAND 8192
#define TILE   128
#define NTILES (N_CAND / TILE)            // 64
#define NLIVE  (NTILES * (NTILES + 1) / 2) // 2080 upper-triangle tiles

// ---------------------------------------------------------------------------
// Pass 1: one block per LIVE tile (bi <= bj), recovered from the linear block
// index via the triangular-number inverse. This removes dead blocks AND the
// mod-256 CU aliasing that pinned all of CU c's blocks to the same bi
// (gridDim.x=64 divides 256), which had left the busiest CUs with 2x the
// average work. Work per block is uniform -> near-perfect CU balance.
// Logits are pre-scaled by log2(e); softplus(d) = ln2*(max(dl,0)+log2(1+2^-|dl|)).
// ---------------------------------------------------------------------------
__global__ __launch_bounds__(TILE) void ranknet_pairs_kernel(
    const float* __restrict__ logits,
    const int*   __restrict__ rankings,
    float*       __restrict__ partials)
{
    const int t = blockIdx.x;              // linear live-tile index
    // invert t = bj*(bj+1)/2 + bi, 0 <= bi <= bj < NTILES
    int bj = (int)((__builtin_sqrtf(8.0f * (float)t + 1.0f) - 1.0f) * 0.5f);
    while ((bj + 1) * (bj + 2) / 2 <= t) ++bj;   // fixups guard fp rounding
    while (bj * (bj + 1) / 2 > t)       --bj;
    const int bi = t - bj * (bj + 1) / 2;

    __shared__ float2 s_j[TILE];          // (logit*log2e, rank) for j-chunk
    __shared__ float  s_part[TILE / 64];

    const float LOG2E = 1.4426950408889634f;
    const int tid = threadIdx.x;

    const int i = bi * TILE + tid;
    const float lis = logits[i] * LOG2E;
    const float ri  = (float)rankings[i];   // ranks < 2^24: exact in f32

    const int j = bj * TILE + tid;
    s_j[tid] = make_float2(logits[j] * LOG2E, (float)rankings[j]);
    __syncthreads();

    float acc = 0.0f;
    if (bi != bj) {
        // off-diagonal: i < j for every pair in the tile
        #pragma unroll 8
        for (int jj = 0; jj < TILE; ++jj) {
            const float2 v = s_j[jj];            // broadcast ds_read_b64
            const float dl = v.x - lis;
            const float e  = __builtin_exp2f(-fabsf(dl));
            const float sp = fmaxf(dl, 0.0f) + __builtin_log2f(1.0f + e);
            const float w  = (v.y > ri) ? __builtin_amdgcn_rcpf(ri + v.y) : 0.0f;
            acc = fmaf(w, sp, acc);
        }
    } else {
        // diagonal tile: also require j > i
        #pragma unroll 8
        for (int jj = 0; jj < TILE; ++jj) {
            const float2 v = s_j[jj];
            const float dl = v.x - lis;
            const float e  = __builtin_exp2f(-fabsf(dl));
            const float sp = fmaxf(dl, 0.0f) + __builtin_log2f(1.0f + e);
            const bool act = (jj > tid) && (v.y > ri);
            const float w  = act ? __builtin_amdgcn_rcpf(ri + v.y) : 0.0f;
            acc = fmaf(w, sp, acc);
        }
    }

    // wave (64-lane) reduction, then cross-wave via LDS
    #pragma unroll
    for (int off = 32; off > 0; off >>= 1)
        acc += __shfl_down(acc, off, 64);
    if ((tid & 63) == 0) s_part[tid >> 6] = acc;
    __syncthreads();
    if (tid == 0) {
        float s = 0.0f;
        #pragma unroll
        for (int w = 0; w < TILE / 64; ++w) s += s_part[w];
        partials[t] = s;
    }
}

// ---------------------------------------------------------------------------
// Pass 2: single block reduces the NLIVE partials; applies ln2 / N once.
// ---------------------------------------------------------------------------
__global__ __launch_bounds__(256) void ranknet_reduce_kernel(
    const float* __restrict__ partials,
    float*       __restrict__ out)
{
    __shared__ float s_part[4];
    const int tid = threadIdx.x;

    float acc = 0.0f;
    for (int k = tid; k < NLIVE; k += 256)
        acc += partials[k];

    #pragma unroll
    for (int off = 32; off > 0; off >>= 1)
        acc += __shfl_down(acc, off, 64);
    if ((tid & 63) == 0) s_part[tid >> 6] = acc;
    __syncthreads();
    if (tid == 0) {
        float s = s_part[0] + s_part[1] + s_part[2] + s_part[3];
        const float LN2 = 0.6931471805599453f;
        out[0] = s * (LN2 / (float)N_CAND);
    }
}

extern "C" void kernel_launch(void* const* d_in, const int* in_sizes, int n_in,
                              void* d_out, int out_size, void* d_ws, size_t ws_size,
                              hipStream_t stream)
{
    const float* logits   = (const float*)d_in[0];
    const int*   rankings = (const int*)  d_in[1];
    float*       out      = (float*)d_out;
    float*       partials = (float*)d_ws;   // NLIVE floats = 8.3 KB

    ranknet_pairs_kernel<<<dim3(NLIVE), dim3(TILE), 0, stream>>>(logits, rankings, partials);
    ranknet_reduce_kernel<<<1, 256, 0, stream>>>(partials, out);
}

// Round 5
// 74.056 us; speedup vs baseline: 1.3586x; 1.1372x over previous
//
#include <hip/hip_runtime.h>

#define N_CAND 8192
#define TILE   128
#define NTILES (N_CAND / TILE)             // 64
#define NLIVE  (NTILES * (NTILES + 1) / 2) // 2080 upper-triangle tiles

// ---------------------------------------------------------------------------
// Pass 1: one block per LIVE tile (bi <= bj), triangular-inverse indexing for
// perfect CU balance. Logits pre-scaled by log2(e) so the inner loop runs in
// the log2 domain:  softplus(d) = ln2 * ( max(dl,0) + log2(1 + 2^-|dl|) ).
//
// Key change this round: RAW transcendental builtins. __builtin_exp2f /
// __builtin_log2f get denormal-fixup legalization sequences without
// -ffast-math (~3x the VALU work); __builtin_amdgcn_exp2f / _logf emit bare
// v_exp_f32 / v_log_f32 (args are in normal range: exp2 in [-90,0], log in
// [1,2]). Masked pairs use rcp(+inf)=0 instead of cmp+cndmask on the weight.
// ---------------------------------------------------------------------------
__global__ __launch_bounds__(TILE) void ranknet_pairs_kernel(
    const float* __restrict__ logits,
    const int*   __restrict__ rankings,
    float*       __restrict__ partials)
{
    const int t = blockIdx.x;              // linear live-tile index
    // invert t = bj*(bj+1)/2 + bi, 0 <= bi <= bj < NTILES
    int bj = (int)((__builtin_sqrtf(8.0f * (float)t + 1.0f) - 1.0f) * 0.5f);
    while ((bj + 1) * (bj + 2) / 2 <= t) ++bj;   // guard fp rounding
    while (bj * (bj + 1) / 2 > t)       --bj;
    const int bi = t - bj * (bj + 1) / 2;

    __shared__ float2 s_j[TILE];           // (logit*log2e, rank) for j-chunk
    __shared__ float  s_part[TILE / 64];

    const float LOG2E = 1.4426950408889634f;
    const float INF   = __builtin_inff();
    const int tid = threadIdx.x;

    const int i = bi * TILE + tid;
    const float lis = logits[i] * LOG2E;
    const float ri  = (float)rankings[i];  // ranks < 2^24: exact in f32

    const int j = bj * TILE + tid;
    s_j[tid] = make_float2(logits[j] * LOG2E, (float)rankings[j]);
    __syncthreads();

    float acc = 0.0f;
    if (bi != bj) {
        // off-diagonal: i < j for every pair in the tile
        #pragma unroll 8
        for (int jj = 0; jj < TILE; ++jj) {
            const float2 v = s_j[jj];                    // broadcast ds_read_b64
            const float dl = v.x - lis;
            const float e  = __builtin_amdgcn_exp2f(-fabsf(dl)); // v_exp_f32, -|.| src mod
            const float lg = __builtin_amdgcn_logf(1.0f + e);    // v_log_f32 (log2)
            const float sp = fmaxf(dl, 0.0f) + lg;
            const float rs = (v.y > ri) ? (ri + v.y) : INF;      // rcp(inf)=0 masks pair
            acc = fmaf(__builtin_amdgcn_rcpf(rs), sp, acc);
        }
    } else {
        // diagonal tile: also require j > i
        #pragma unroll 8
        for (int jj = 0; jj < TILE; ++jj) {
            const float2 v = s_j[jj];
            const float dl = v.x - lis;
            const float e  = __builtin_amdgcn_exp2f(-fabsf(dl));
            const float lg = __builtin_amdgcn_logf(1.0f + e);
            const float sp = fmaxf(dl, 0.0f) + lg;
            const bool act = (jj > tid) && (v.y > ri);
            const float rs = act ? (ri + v.y) : INF;
            acc = fmaf(__builtin_amdgcn_rcpf(rs), sp, acc);
        }
    }

    // wave (64-lane) reduction, then cross-wave via LDS
    #pragma unroll
    for (int off = 32; off > 0; off >>= 1)
        acc += __shfl_down(acc, off, 64);
    if ((tid & 63) == 0) s_part[tid >> 6] = acc;
    __syncthreads();
    if (tid == 0) {
        float s = 0.0f;
        #pragma unroll
        for (int w = 0; w < TILE / 64; ++w) s += s_part[w];
        partials[t] = s;
    }
}

// ---------------------------------------------------------------------------
// Pass 2: single block reduces the NLIVE partials; applies ln2 / N once.
// ---------------------------------------------------------------------------
__global__ __launch_bounds__(256) void ranknet_reduce_kernel(
    const float* __restrict__ partials,
    float*       __restrict__ out)
{
    __shared__ float s_part[4];
    const int tid = threadIdx.x;

    float acc = 0.0f;
    for (int k = tid; k < NLIVE; k += 256)
        acc += partials[k];

    #pragma unroll
    for (int off = 32; off > 0; off >>= 1)
        acc += __shfl_down(acc, off, 64);
    if ((tid & 63) == 0) s_part[tid >> 6] = acc;
    __syncthreads();
    if (tid == 0) {
        float s = s_part[0] + s_part[1] + s_part[2] + s_part[3];
        const float LN2 = 0.6931471805599453f;
        out[0] = s * (LN2 / (float)N_CAND);
    }
}

extern "C" void kernel_launch(void* const* d_in, const int* in_sizes, int n_in,
                              void* d_out, int out_size, void* d_ws, size_t ws_size,
                              hipStream_t stream)
{
    const float* logits   = (const float*)d_in[0];
    const int*   rankings = (const int*)  d_in[1];
    float*       out      = (float*)d_out;
    float*       partials = (float*)d_ws;   // NLIVE floats = 8.3 KB

    ranknet_pairs_kernel<<<dim3(NLIVE), dim3(TILE), 0, stream>>>(logits, rankings, partials);
    ranknet_reduce_kernel<<<1, 256, 0, stream>>>(partials, out);
}